// Round 8
// baseline (344.193 us; speedup 1.0000x reference)
//
#include <hip/hip_runtime.h>

using bf16x8 = __attribute__((ext_vector_type(8))) __bf16;
using f32x4  = __attribute__((ext_vector_type(4))) float;

#define NE 1024
#define C1E 0.18033688011112042f   // 0.125 * log2(e)
#define C2E -11.541560327111707f   // -8 * log2(e)

__device__ __forceinline__ unsigned short f2b(float f) {
    unsigned u = __builtin_bit_cast(unsigned, f);
    u = (u + 0x7FFFu + ((u >> 16) & 1u)) >> 16;
    return (unsigned short)u;
}

typedef __attribute__((address_space(1))) const void gvoid_t;
typedef __attribute__((address_space(3))) void lvoid_t;

// All stage helpers: source pre-swizzled so LDS satisfies
//   lds[row*RB + (x ^ ((row&7)<<4))] = g[row][x]   (RB = row bytes)

// 128 rows x 128B, row stride NE bf16. 16 KB.
__device__ __forceinline__ void stage128(const unsigned short* gbase, char* lds, int tid)
{
    const int w = tid >> 6, l = tid & 63;
    #pragma unroll
    for (int i = 0; i < 4; ++i) {
        int grp = i * 4 + w;
        int row = grp * 8 + (l >> 3);
        int srcb = ((l & 7) * 16) ^ ((l >> 3) << 4);
        const char* g = (const char*)(gbase + (size_t)row * NE) + srcb;
        __builtin_amdgcn_global_load_lds((gvoid_t*)g, (lvoid_t*)(lds + grp * 1024), 16, 0, 0);
    }
}

// 64 rows x 128B, row stride NE. 8 KB.
__device__ __forceinline__ void stage64x128(const unsigned short* gbase, char* lds, int tid)
{
    const int w = tid >> 6, l = tid & 63;
    #pragma unroll
    for (int i = 0; i < 2; ++i) {
        int grp = i * 4 + w;
        int row = grp * 8 + (l >> 3);
        int srcb = ((l & 7) * 16) ^ ((l >> 3) << 4);
        const char* g = (const char*)(gbase + (size_t)row * NE) + srcb;
        __builtin_amdgcn_global_load_lds((gvoid_t*)g, (lvoid_t*)(lds + grp * 1024), 16, 0, 0);
    }
}

// 32 rows x 128B, row stride NE. 4 KB.
__device__ __forceinline__ void stage32(const unsigned short* gbase, char* lds, int tid)
{
    const int w = tid >> 6, l = tid & 63;
    int row = w * 8 + (l >> 3);
    int srcb = ((l & 7) * 16) ^ ((l >> 3) << 4);
    const char* g = (const char*)(gbase + (size_t)row * NE) + srcb;
    __builtin_amdgcn_global_load_lds((gvoid_t*)g, (lvoid_t*)(lds + w * 1024), 16, 0, 0);
}

// 64 rows x 256B, row stride 1024 bf16. 16 KB.
__device__ __forceinline__ void stage64x256(const unsigned short* gbase, char* lds, int tid)
{
    const int w = tid >> 6, l = tid & 63;
    #pragma unroll
    for (int i = 0; i < 4; ++i) {
        int row0 = i * 16 + w * 4;
        int row = row0 + (l >> 4);
        int srcb = ((l & 15) * 16) ^ ((row & 7) << 4);
        const char* g = (const char*)(gbase + (size_t)row * 1024) + srcb;
        __builtin_amdgcn_global_load_lds((gvoid_t*)g, (lvoid_t*)(lds + row0 * 256), 16, 0, 0);
    }
}

// f32 -> bf16 (RNE), 8 elems/thread.
__global__ __launch_bounds__(256)
void conv_bf16(const float* __restrict__ src, unsigned short* __restrict__ dst)
{
    size_t i = ((size_t)blockIdx.x * 256 + threadIdx.x) * 8;
    float4 a0 = *(const float4*)(src + i);
    float4 a1 = *(const float4*)(src + i + 4);
    uint4 p;
    p.x = f2b(a0.x) | ((unsigned)f2b(a0.y) << 16);
    p.y = f2b(a0.z) | ((unsigned)f2b(a0.w) << 16);
    p.z = f2b(a1.x) | ((unsigned)f2b(a1.y) << 16);
    p.w = f2b(a1.z) | ((unsigned)f2b(a1.w) << 16);
    *(uint4*)(dst + i) = p;
}

// q + Wq + Wk + Wv conversion in one launch. grid 4096 + 3*512.
__global__ __launch_bounds__(256)
void conv_all(const float* __restrict__ q, const float* __restrict__ w0,
              const float* __restrict__ w1, const float* __restrict__ w2,
              unsigned short* __restrict__ qd, unsigned short* __restrict__ d0,
              unsigned short* __restrict__ d1, unsigned short* __restrict__ d2)
{
    int bid = blockIdx.x;
    const float* s; unsigned short* d; size_t off;
    if (bid < 4096) { s = q; d = qd; off = (size_t)bid * 2048; }
    else {
        int seg = (bid - 4096) >> 9, r = (bid - 4096) & 511;
        s = seg == 0 ? w0 : (seg == 1 ? w1 : w2);
        d = seg == 0 ? d0 : (seg == 1 ? d1 : d2);
        off = (size_t)r * 2048;
    }
    size_t i = off + threadIdx.x * 8;
    float4 a0 = *(const float4*)(s + i);
    float4 a1 = *(const float4*)(s + i + 4);
    uint4 p;
    p.x = f2b(a0.x) | ((unsigned)f2b(a0.y) << 16);
    p.y = f2b(a0.z) | ((unsigned)f2b(a0.w) << 16);
    p.z = f2b(a1.x) | ((unsigned)f2b(a1.y) << 16);
    p.w = f2b(a1.z) | ((unsigned)f2b(a1.w) << 16);
    *(uint4*)(d + i) = p;
}

// Fused QKV projection: block = 128 A-rows x 64 cols, all three weights.
// grid 1024 linear, XCD-swizzled. Q,K bf16 row-major; V in V^T layout.
__global__ __launch_bounds__(256, 2)
void qkv_proj(const unsigned short* __restrict__ A,
              const unsigned short* __restrict__ Wq, const unsigned short* __restrict__ Wk,
              const unsigned short* __restrict__ Wv,
              const float* __restrict__ bq, const float* __restrict__ bk,
              const float* __restrict__ bv,
              unsigned short* __restrict__ Qo, unsigned short* __restrict__ Ko,
              unsigned short* __restrict__ Vo)
{
    __shared__ char Asm[16384];
    __shared__ char Bsm[3][8192];
    const int tid  = threadIdx.x;
    const int lane = tid & 63;
    const int w    = tid >> 6;
    const int swz = (blockIdx.x & 7) * 128 + (blockIdx.x >> 3);
    const int rowbase = (swz >> 4) * 128;
    const int colbase = (swz & 15) * 64;
    f32x4 acc[3][2][4] = {};

    for (int kt = 0; kt < 16; ++kt) {
        __syncthreads();
        stage128(A + (size_t)rowbase * NE + kt * 64, Asm, tid);
        stage64x128(Wq + (size_t)colbase * NE + kt * 64, Bsm[0], tid);
        stage64x128(Wk + (size_t)colbase * NE + kt * 64, Bsm[1], tid);
        stage64x128(Wv + (size_t)colbase * NE + kt * 64, Bsm[2], tid);
        __syncthreads();
        #pragma unroll
        for (int ks = 0; ks < 2; ++ks) {
            const int kb = ks * 64 + (lane >> 4) * 16;
            bf16x8 af[2], bf[3][4];
            #pragma unroll
            for (int m = 0; m < 2; ++m) {
                int row = w * 32 + m * 16 + (lane & 15);
                af[m] = *(const bf16x8*)(Asm + ((row * 128 + kb) ^ ((row & 7) << 4)));
            }
            #pragma unroll
            for (int j = 0; j < 3; ++j)
                #pragma unroll
                for (int n = 0; n < 4; ++n) {
                    int row = n * 16 + (lane & 15);
                    bf[j][n] = *(const bf16x8*)(Bsm[j] + ((row * 128 + kb) ^ ((row & 7) << 4)));
                }
            #pragma unroll
            for (int j = 0; j < 3; ++j)
                #pragma unroll
                for (int m = 0; m < 2; ++m)
                    #pragma unroll
                    for (int n = 0; n < 4; ++n)
                        acc[j][m][n] = __builtin_amdgcn_mfma_f32_16x16x32_bf16(af[m], bf[j][n], acc[j][m][n], 0, 0, 0);
        }
    }

    #pragma unroll
    for (int m = 0; m < 2; ++m)
        #pragma unroll
        for (int n = 0; n < 4; ++n) {
            int col = colbase + n * 16 + (lane & 15);
            float bvq = bq[col], bvk = bk[col], bvv = bv[col];
            #pragma unroll
            for (int r = 0; r < 4; ++r) {
                int row = rowbase + w * 32 + m * 16 + (lane >> 4) * 4 + r;
                Qo[(size_t)row * NE + col] = f2b(acc[0][m][n][r] + bvq);
                Ko[(size_t)row * NE + col] = f2b(acc[1][m][n][r] + bvk);
                int b = row >> 10, s = row & 1023, h = col >> 6, d = col & 63;
                Vo[((size_t)((b * 16 + h) * 64 + d) << 10) + s] = f2b(acc[2][m][n][r] + bvv);
            }
        }
}

// O-projection GEMM (bf16 A,W; f32 out). grid 512 linear, XCD-swizzled.
__global__ __launch_bounds__(256)
void proj_o(const unsigned short* __restrict__ A, const unsigned short* __restrict__ W,
            const float* __restrict__ bias, float* __restrict__ outp)
{
    __shared__ char Asm[16384], Bsm[16384];
    const int tid  = threadIdx.x;
    const int lane = tid & 63;
    const int wid  = tid >> 6;
    const int wr = wid >> 1, wc = wid & 1;
    const int swz = (blockIdx.x & 7) * 64 + (blockIdx.x >> 3);
    const int rowbase = (swz >> 3) * 128;
    const int colbase = (swz & 7) * 128;
    f32x4 acc[4][4] = {};

    for (int kt = 0; kt < 16; ++kt) {
        __syncthreads();
        stage128(A + (size_t)rowbase * NE + kt * 64, Asm, tid);
        stage128(W + (size_t)colbase * NE + kt * 64, Bsm, tid);
        __syncthreads();
        #pragma unroll
        for (int ks = 0; ks < 2; ++ks) {
            const int kb = ks * 64 + (lane >> 4) * 16;
            bf16x8 af[4], bf[4];
            #pragma unroll
            for (int m = 0; m < 4; ++m) {
                int row = wr * 64 + m * 16 + (lane & 15);
                af[m] = *(const bf16x8*)(Asm + ((row * 128 + kb) ^ ((row & 7) << 4)));
            }
            #pragma unroll
            for (int n = 0; n < 4; ++n) {
                int row = wc * 64 + n * 16 + (lane & 15);
                bf[n] = *(const bf16x8*)(Bsm + ((row * 128 + kb) ^ ((row & 7) << 4)));
            }
            #pragma unroll
            for (int m = 0; m < 4; ++m)
                #pragma unroll
                for (int n = 0; n < 4; ++n)
                    acc[m][n] = __builtin_amdgcn_mfma_f32_16x16x32_bf16(af[m], bf[n], acc[m][n], 0, 0, 0);
        }
    }

    #pragma unroll
    for (int m = 0; m < 4; ++m)
        #pragma unroll
        for (int n = 0; n < 4; ++n) {
            int col = colbase + wc * 64 + n * 16 + (lane & 15);
            float bv = bias[col];
            #pragma unroll
            for (int r = 0; r < 4; ++r) {
                int row = rowbase + wr * 64 + m * 16 + (lane >> 4) * 4 + r;
                outp[(size_t)row * NE + col] = acc[m][n][r] + bv;
            }
        }
}

// Fused attention, S-in-registers. grid 4096 linear, XCD-swizzled (16 bh/XCD).
// Block = 32 q-rows of one (b,h). Loop A: QK^T once, e=exp2(s*C1+C2) in-place
// into sacc, row sums. Loop B: p = e*il, write attn f32, pack P->LDS, PV with
// double-buffered async V. O (bf16) into Og (aliases Q ws; own-tile only).
__global__ __launch_bounds__(256, 2)
void fused_attn(const unsigned short* __restrict__ Q,
                const unsigned short* __restrict__ K,
                const unsigned short* __restrict__ VT,
                float* __restrict__ attn, unsigned short* __restrict__ Og)
{
    __shared__ char Ksm[16384];
    __shared__ char Vsm[2][16384];
    __shared__ char Psm[8192];           // Q staged here first; then P tiles
    __shared__ float rs4[4][32];
    __shared__ float il[32];
    const int tid  = threadIdx.x;
    const int lane = tid & 63;
    const int w    = tid >> 6;
    const int swzb = (blockIdx.x & 7) * 512 + (blockIdx.x >> 3);
    const int bh = swzb >> 5, qt = swzb & 31;
    const int b = bh >> 4, h = bh & 15;
    const unsigned short* Qg = Q  + (size_t)(b * 1024 + qt * 32) * 1024 + h * 64;
    const unsigned short* Kg = K  + (size_t)(b * 1024) * 1024 + h * 64;
    const unsigned short* Vg = VT + (size_t)bh * 64 * 1024;

    stage32(Qg, Psm, tid);
    stage128(Kg, Ksm, tid);              // K(0)
    __syncthreads();
    bf16x8 qf[2][2];
    #pragma unroll
    for (int ks = 0; ks < 2; ++ks) {
        const int kb = ks * 64 + (lane >> 4) * 16;
        #pragma unroll
        for (int n = 0; n < 2; ++n) {
            int row = n * 16 + (lane & 15);
            qf[ks][n] = *(const bf16x8*)(Psm + ((row * 128 + kb) ^ ((row & 7) << 4)));
        }
    }

    // ---- loop A: S once, e in-place, row sums ----
    f32x4 sacc[8][2][2] = {};
    float rs_p[2] = {0.f, 0.f};
    #pragma unroll
    for (int kt = 0; kt < 8; ++kt) {
        __builtin_amdgcn_s_setprio(1);
        #pragma unroll
        for (int ks = 0; ks < 2; ++ks) {
            const int kb = ks * 64 + (lane >> 4) * 16;
            bf16x8 kf[2];
            #pragma unroll
            for (int m = 0; m < 2; ++m) {
                int row = w * 32 + m * 16 + (lane & 15);
                kf[m] = *(const bf16x8*)(Ksm + ((row * 128 + kb) ^ ((row & 7) << 4)));
            }
            #pragma unroll
            for (int m = 0; m < 2; ++m)
                #pragma unroll
                for (int n = 0; n < 2; ++n)
                    sacc[kt][m][n] = __builtin_amdgcn_mfma_f32_16x16x32_bf16(kf[m], qf[ks][n], sacc[kt][m][n], 0, 0, 0);
        }
        __builtin_amdgcn_s_setprio(0);
        __syncthreads();                 // Ksm reads done
        if (kt < 7) stage128(Kg + (size_t)((kt + 1) * 128) * 1024, Ksm, tid);
        else        stage64x256(Vg, Vsm[0], tid);     // V(0) prefetch
        #pragma unroll
        for (int m = 0; m < 2; ++m)
            #pragma unroll
            for (int n = 0; n < 2; ++n)
                #pragma unroll
                for (int r = 0; r < 4; ++r) {
                    float e = exp2f(fmaf(sacc[kt][m][n][r], C1E, C2E));
                    sacc[kt][m][n][r] = e;
                    rs_p[n] += e;
                }
        __syncthreads();                 // next K staged + drained
    }

    #pragma unroll
    for (int n = 0; n < 2; ++n) {
        rs_p[n] += __shfl_xor(rs_p[n], 16);
        rs_p[n] += __shfl_xor(rs_p[n], 32);
    }
    if (lane < 16) {
        rs4[w][lane]      = rs_p[0];
        rs4[w][16 + lane] = rs_p[1];
    }
    __syncthreads();
    if (tid < 32) il[tid] = 1.0f / (rs4[0][tid] + rs4[1][tid] + rs4[2][tid] + rs4[3][tid]);
    __syncthreads();                     // il visible; V(0) drained

    // ---- loop B: attn write + PV ----
    f32x4 oa[2] = {};                    // 32q x 16d per wave (d-tile = w*16)
    float* attnq = attn + ((size_t)bh * 1024 + qt * 32) * 1024;
    #pragma unroll
    for (int kt = 0; kt < 8; ++kt) {
        #pragma unroll
        for (int n = 0; n < 2; ++n) {
            int q = n * 16 + (lane & 15);
            float iv = il[q];
            #pragma unroll
            for (int m = 0; m < 2; ++m) {
                int k0 = w * 32 + m * 16 + (lane >> 4) * 4;
                float4 p4;
                p4.x = sacc[kt][m][n][0] * iv;
                p4.y = sacc[kt][m][n][1] * iv;
                p4.z = sacc[kt][m][n][2] * iv;
                p4.w = sacc[kt][m][n][3] * iv;
                *(float4*)(attnq + (size_t)q * 1024 + kt * 128 + k0) = p4;
                uint2 pk;
                pk.x = f2b(p4.x) | ((unsigned)f2b(p4.y) << 16);
                pk.y = f2b(p4.z) | ((unsigned)f2b(p4.w) << 16);
                *(uint2*)(Psm + ((q * 256 + k0 * 2) ^ ((q & 7) << 4))) = pk;
            }
        }
        __syncthreads();                 // Psm ready; V(kt) already resident
        if (kt < 7) stage64x256(Vg + (kt + 1) * 128, Vsm[(kt + 1) & 1], tid);
        __builtin_amdgcn_s_setprio(1);
        #pragma unroll
        for (int ks = 0; ks < 4; ++ks) {
            const int kb = ks * 64 + (lane >> 4) * 16;
            bf16x8 pa[2], vb;
            #pragma unroll
            for (int m2 = 0; m2 < 2; ++m2) {
                int row = m2 * 16 + (lane & 15);
                pa[m2] = *(const bf16x8*)(Psm + ((row * 256 + kb) ^ ((row & 7) << 4)));
            }
            {
                int d = w * 16 + (lane & 15);
                vb = *(const bf16x8*)(Vsm[kt & 1] + d * 256 + (kb ^ ((d & 7) << 4)));
            }
            #pragma unroll
            for (int m2 = 0; m2 < 2; ++m2)
                oa[m2] = __builtin_amdgcn_mfma_f32_16x16x32_bf16(pa[m2], vb, oa[m2], 0, 0, 0);
        }
        __builtin_amdgcn_s_setprio(0);
        __syncthreads();                 // Psm free; V(kt+1) drained
    }

    unsigned short* Ob = Og + (size_t)(b * 1024 + qt * 32) * 1024 + h * 64;
    #pragma unroll
    for (int m2 = 0; m2 < 2; ++m2) {
        int d = w * 16 + (lane & 15);
        #pragma unroll
        for (int r = 0; r < 4; ++r) {
            int qrow = m2 * 16 + (lane >> 4) * 4 + r;
            Ob[(size_t)qrow * 1024 + d] = f2b(oa[m2][r]);
        }
    }
}

extern "C" void kernel_launch(void* const* d_in, const int* in_sizes, int n_in,
                              void* d_out, int out_size, void* d_ws, size_t ws_size,
                              hipStream_t stream) {
    (void)in_sizes; (void)n_in; (void)out_size; (void)ws_size;
    const float* q    = (const float*)d_in[0];
    const float* Wq_w = (const float*)d_in[1];
    const float* Wq_b = (const float*)d_in[2];
    const float* Wk_w = (const float*)d_in[3];
    const float* Wk_b = (const float*)d_in[4];
    const float* Wv_w = (const float*)d_in[5];
    const float* Wv_b = (const float*)d_in[6];
    const float* Wo_w = (const float*)d_in[7];
    const float* Wo_b = (const float*)d_in[8];

    char* ws = (char*)d_ws;                              // ws use: 48 MiB
    unsigned short* Qws  = (unsigned short*)(ws);        // Q bf16, later O bf16
    unsigned short* Kws  = (unsigned short*)(ws + (16u << 20));  // K bf16, later Wo bf16
    unsigned short* VTws = (unsigned short*)(ws + (32u << 20));

    float* outp  = (float*)d_out;                        // f32 out [8,1024,1024]
    float* attnp = outp + 8388608;                       // f32 attn [8,16,1024,1024]

    // bf16 scratch inside attn region (free until fused_attn writes it)
    char* scr = (char*)attnp;
    unsigned short* qbf = (unsigned short*)scr;                    // 16 MiB
    unsigned short* wqb = (unsigned short*)(scr + (16u << 20));
    unsigned short* wkb = (unsigned short*)(scr + (18u << 20));
    unsigned short* wvb = (unsigned short*)(scr + (20u << 20));

    dim3 blk(256);
    conv_all<<<dim3(4096 + 3 * 512), blk, 0, stream>>>(q, Wq_w, Wk_w, Wv_w, qbf, wqb, wkb, wvb);
    qkv_proj<<<dim3(1024), blk, 0, stream>>>(qbf, wqb, wkb, wvb, Wq_b, Wk_b, Wv_b, Qws, Kws, VTws);
    fused_attn<<<dim3(4096), blk, 0, stream>>>(Qws, Kws, VTws, attnp, Qws);
    conv_bf16<<<dim3(512), blk, 0, stream>>>(Wo_w, Kws);           // Kws free now
    proj_o<<<dim3(512), blk, 0, stream>>>(Qws, Kws, Wo_b, outp);
}

// Round 9
// 277.951 us; speedup vs baseline: 1.2383x; 1.2383x over previous
//
#include <hip/hip_runtime.h>

using bf16x8 = __attribute__((ext_vector_type(8))) __bf16;
using f32x4  = __attribute__((ext_vector_type(4))) float;

#define NE 1024
#define C1E 0.18033688011112042f   // 0.125 * log2(e)
#define C2E -11.541560327111707f   // -8 * log2(e)

__device__ __forceinline__ unsigned short f2b(float f) {
    unsigned u = __builtin_bit_cast(unsigned, f);
    u = (u + 0x7FFFu + ((u >> 16) & 1u)) >> 16;
    return (unsigned short)u;
}

typedef __attribute__((address_space(1))) const void gvoid_t;
typedef __attribute__((address_space(3))) void lvoid_t;

// Stage helpers: source pre-swizzled so LDS satisfies
//   lds[row*RB + (x ^ ((row&7)<<4))] = g[row][x]

// 128 rows x 128B, row stride NE bf16. 16 KB.
__device__ __forceinline__ void stage128(const unsigned short* gbase, char* lds, int tid)
{
    const int w = tid >> 6, l = tid & 63;
    #pragma unroll
    for (int i = 0; i < 4; ++i) {
        int grp = i * 4 + w;
        int row = grp * 8 + (l >> 3);
        int srcb = ((l & 7) * 16) ^ ((l >> 3) << 4);
        const char* g = (const char*)(gbase + (size_t)row * NE) + srcb;
        __builtin_amdgcn_global_load_lds((gvoid_t*)g, (lvoid_t*)(lds + grp * 1024), 16, 0, 0);
    }
}

// 64 rows x 128B, row stride NE. 8 KB.
__device__ __forceinline__ void stage64x128(const unsigned short* gbase, char* lds, int tid)
{
    const int w = tid >> 6, l = tid & 63;
    #pragma unroll
    for (int i = 0; i < 2; ++i) {
        int grp = i * 4 + w;
        int row = grp * 8 + (l >> 3);
        int srcb = ((l & 7) * 16) ^ ((l >> 3) << 4);
        const char* g = (const char*)(gbase + (size_t)row * NE) + srcb;
        __builtin_amdgcn_global_load_lds((gvoid_t*)g, (lvoid_t*)(lds + grp * 1024), 16, 0, 0);
    }
}

// 64 rows x 256B, row stride 1024 bf16. 16 KB.
__device__ __forceinline__ void stage64x256(const unsigned short* gbase, char* lds, int tid)
{
    const int w = tid >> 6, l = tid & 63;
    #pragma unroll
    for (int i = 0; i < 4; ++i) {
        int row0 = i * 16 + w * 4;
        int row = row0 + (l >> 4);
        int srcb = ((l & 15) * 16) ^ ((row & 7) << 4);
        const char* g = (const char*)(gbase + (size_t)row * 1024) + srcb;
        __builtin_amdgcn_global_load_lds((gvoid_t*)g, (lvoid_t*)(lds + row0 * 256), 16, 0, 0);
    }
}

// f32 -> bf16 (RNE), 8 elems/thread.
__global__ __launch_bounds__(256)
void conv_bf16(const float* __restrict__ src, unsigned short* __restrict__ dst)
{
    size_t i = ((size_t)blockIdx.x * 256 + threadIdx.x) * 8;
    float4 a0 = *(const float4*)(src + i);
    float4 a1 = *(const float4*)(src + i + 4);
    uint4 p;
    p.x = f2b(a0.x) | ((unsigned)f2b(a0.y) << 16);
    p.y = f2b(a0.z) | ((unsigned)f2b(a0.w) << 16);
    p.z = f2b(a1.x) | ((unsigned)f2b(a1.y) << 16);
    p.w = f2b(a1.z) | ((unsigned)f2b(a1.w) << 16);
    *(uint4*)(dst + i) = p;
}

// q + Wq + Wk + Wv conversion in one launch. grid 4096 + 3*512.
__global__ __launch_bounds__(256)
void conv_all(const float* __restrict__ q, const float* __restrict__ w0,
              const float* __restrict__ w1, const float* __restrict__ w2,
              unsigned short* __restrict__ qd, unsigned short* __restrict__ d0,
              unsigned short* __restrict__ d1, unsigned short* __restrict__ d2)
{
    int bid = blockIdx.x;
    const float* s; unsigned short* d; size_t off;
    if (bid < 4096) { s = q; d = qd; off = (size_t)bid * 2048; }
    else {
        int seg = (bid - 4096) >> 9, r = (bid - 4096) & 511;
        s = seg == 0 ? w0 : (seg == 1 ? w1 : w2);
        d = seg == 0 ? d0 : (seg == 1 ? d1 : d2);
        off = (size_t)r * 2048;
    }
    size_t i = off + threadIdx.x * 8;
    float4 a0 = *(const float4*)(s + i);
    float4 a1 = *(const float4*)(s + i + 4);
    uint4 p;
    p.x = f2b(a0.x) | ((unsigned)f2b(a0.y) << 16);
    p.y = f2b(a0.z) | ((unsigned)f2b(a0.w) << 16);
    p.z = f2b(a1.x) | ((unsigned)f2b(a1.y) << 16);
    p.w = f2b(a1.z) | ((unsigned)f2b(a1.w) << 16);
    *(uint4*)(d + i) = p;
}

// Fused QKV projection: block = 128 A-rows x 64 cols, all three weights.
// grid 1024 linear, XCD-swizzled. Q,K bf16 row-major; V in V^T layout.
__global__ __launch_bounds__(256, 2)
void qkv_proj(const unsigned short* __restrict__ A,
              const unsigned short* __restrict__ Wq, const unsigned short* __restrict__ Wk,
              const unsigned short* __restrict__ Wv,
              const float* __restrict__ bq, const float* __restrict__ bk,
              const float* __restrict__ bv,
              unsigned short* __restrict__ Qo, unsigned short* __restrict__ Ko,
              unsigned short* __restrict__ Vo)
{
    __shared__ char Asm[16384];
    __shared__ char Bsm[3][8192];
    const int tid  = threadIdx.x;
    const int lane = tid & 63;
    const int w    = tid >> 6;
    const int swz = (blockIdx.x & 7) * 128 + (blockIdx.x >> 3);
    const int rowbase = (swz >> 4) * 128;
    const int colbase = (swz & 15) * 64;
    f32x4 acc[3][2][4] = {};

    for (int kt = 0; kt < 16; ++kt) {
        __syncthreads();
        stage128(A + (size_t)rowbase * NE + kt * 64, Asm, tid);
        stage64x128(Wq + (size_t)colbase * NE + kt * 64, Bsm[0], tid);
        stage64x128(Wk + (size_t)colbase * NE + kt * 64, Bsm[1], tid);
        stage64x128(Wv + (size_t)colbase * NE + kt * 64, Bsm[2], tid);
        __syncthreads();
        #pragma unroll
        for (int ks = 0; ks < 2; ++ks) {
            const int kb = ks * 64 + (lane >> 4) * 16;
            bf16x8 af[2], bf[3][4];
            #pragma unroll
            for (int m = 0; m < 2; ++m) {
                int row = w * 32 + m * 16 + (lane & 15);
                af[m] = *(const bf16x8*)(Asm + ((row * 128 + kb) ^ ((row & 7) << 4)));
            }
            #pragma unroll
            for (int j = 0; j < 3; ++j)
                #pragma unroll
                for (int n = 0; n < 4; ++n) {
                    int row = n * 16 + (lane & 15);
                    bf[j][n] = *(const bf16x8*)(Bsm[j] + ((row * 128 + kb) ^ ((row & 7) << 4)));
                }
            #pragma unroll
            for (int j = 0; j < 3; ++j)
                #pragma unroll
                for (int m = 0; m < 2; ++m)
                    #pragma unroll
                    for (int n = 0; n < 4; ++n)
                        acc[j][m][n] = __builtin_amdgcn_mfma_f32_16x16x32_bf16(af[m], bf[j][n], acc[j][m][n], 0, 0, 0);
        }
    }

    #pragma unroll
    for (int m = 0; m < 2; ++m)
        #pragma unroll
        for (int n = 0; n < 4; ++n) {
            int col = colbase + n * 16 + (lane & 15);
            float bvq = bq[col], bvk = bk[col], bvv = bv[col];
            #pragma unroll
            for (int r = 0; r < 4; ++r) {
                int row = rowbase + w * 32 + m * 16 + (lane >> 4) * 4 + r;
                Qo[(size_t)row * NE + col] = f2b(acc[0][m][n][r] + bvq);
                Ko[(size_t)row * NE + col] = f2b(acc[1][m][n][r] + bvk);
                int b = row >> 10, s = row & 1023, h = col >> 6, d = col & 63;
                Vo[((size_t)((b * 16 + h) * 64 + d) << 10) + s] = f2b(acc[2][m][n][r] + bvv);
            }
        }
}

// O-projection GEMM (bf16 A,W; f32 out). grid 512 linear, XCD-swizzled.
__global__ __launch_bounds__(256)
void proj_o(const unsigned short* __restrict__ A, const unsigned short* __restrict__ W,
            const float* __restrict__ bias, float* __restrict__ outp)
{
    __shared__ char Asm[16384], Bsm[16384];
    const int tid  = threadIdx.x;
    const int lane = tid & 63;
    const int wid  = tid >> 6;
    const int wr = wid >> 1, wc = wid & 1;
    const int swz = (blockIdx.x & 7) * 64 + (blockIdx.x >> 3);
    const int rowbase = (swz >> 3) * 128;
    const int colbase = (swz & 7) * 128;
    f32x4 acc[4][4] = {};

    for (int kt = 0; kt < 16; ++kt) {
        __syncthreads();
        stage128(A + (size_t)rowbase * NE + kt * 64, Asm, tid);
        stage128(W + (size_t)colbase * NE + kt * 64, Bsm, tid);
        __syncthreads();
        #pragma unroll
        for (int ks = 0; ks < 2; ++ks) {
            const int kb = ks * 64 + (lane >> 4) * 16;
            bf16x8 af[4], bf[4];
            #pragma unroll
            for (int m = 0; m < 4; ++m) {
                int row = wr * 64 + m * 16 + (lane & 15);
                af[m] = *(const bf16x8*)(Asm + ((row * 128 + kb) ^ ((row & 7) << 4)));
            }
            #pragma unroll
            for (int n = 0; n < 4; ++n) {
                int row = wc * 64 + n * 16 + (lane & 15);
                bf[n] = *(const bf16x8*)(Bsm + ((row * 128 + kb) ^ ((row & 7) << 4)));
            }
            #pragma unroll
            for (int m = 0; m < 4; ++m)
                #pragma unroll
                for (int n = 0; n < 4; ++n)
                    acc[m][n] = __builtin_amdgcn_mfma_f32_16x16x32_bf16(af[m], bf[n], acc[m][n], 0, 0, 0);
        }
    }

    #pragma unroll
    for (int m = 0; m < 4; ++m)
        #pragma unroll
        for (int n = 0; n < 4; ++n) {
            int col = colbase + wc * 64 + n * 16 + (lane & 15);
            float bv = bias[col];
            #pragma unroll
            for (int r = 0; r < 4; ++r) {
                int row = rowbase + wr * 64 + m * 16 + (lane >> 4) * 4 + r;
                outp[(size_t)row * NE + col] = acc[m][n][r] + bv;
            }
        }
}

// Fused attention (round-7 structure). grid 1024 linear, XCD-swizzled (16 bh/XCD).
// Per block: 128 q-rows of one (b,h). Q fragments in registers; K staged+prefetched;
// V staged async per kt; normalization folded into exp2 exponent (lt[q]).
__global__ __launch_bounds__(256, 2)
void fused_attn(const unsigned short* __restrict__ Q,
                const unsigned short* __restrict__ K,
                const unsigned short* __restrict__ VT,
                float* __restrict__ attn, unsigned short* __restrict__ Og)
{
    __shared__ char Ksm[16384];
    __shared__ char Vsm[16384];
    __shared__ char Psm[32768];          // Q staged here initially; then P tiles
    __shared__ float rs4[4][128];
    __shared__ float lt[128];
    const int tid  = threadIdx.x;
    const int lane = tid & 63;
    const int w    = tid >> 6;
    const int swzb = (blockIdx.x & 7) * 128 + (blockIdx.x >> 3);
    const int bh = swzb >> 3, qt = swzb & 7;
    const int b = bh >> 4, h = bh & 15;
    const unsigned short* Qg = Q  + (size_t)(b * 1024 + qt * 128) * 1024 + h * 64;
    const unsigned short* Kg = K  + (size_t)(b * 1024) * 1024 + h * 64;
    const unsigned short* Vg = VT + (size_t)bh * 64 * 1024;

    // stage Q via Psm, hoist fragments to registers
    stage128(Qg, Psm, tid);
    __syncthreads();
    bf16x8 qf[2][8];
    #pragma unroll
    for (int ks = 0; ks < 2; ++ks) {
        const int kb = ks * 64 + (lane >> 4) * 16;
        #pragma unroll
        for (int n = 0; n < 8; ++n) {
            int row = n * 16 + (lane & 15);
            qf[ks][n] = *(const bf16x8*)(Psm + ((row * 128 + kb) ^ ((row & 7) << 4)));
        }
    }
    stage128(Kg, Ksm, tid);   // K(0)

    // ---- loop 1: row sums of exp2(s*C1 + C2) ----
    float rs_p[8] = {0.f, 0.f, 0.f, 0.f, 0.f, 0.f, 0.f, 0.f};
    for (int kt = 0; kt < 8; ++kt) {
        __syncthreads();                       // K(kt) ready
        f32x4 sa[2][8] = {};
        __builtin_amdgcn_s_setprio(1);
        #pragma unroll
        for (int ks = 0; ks < 2; ++ks) {
            const int kb = ks * 64 + (lane >> 4) * 16;
            bf16x8 kf[2];
            #pragma unroll
            for (int m = 0; m < 2; ++m) {
                int row = w * 32 + m * 16 + (lane & 15);
                kf[m] = *(const bf16x8*)(Ksm + ((row * 128 + kb) ^ ((row & 7) << 4)));
            }
            #pragma unroll
            for (int m = 0; m < 2; ++m)
                #pragma unroll
                for (int n = 0; n < 8; ++n)
                    sa[m][n] = __builtin_amdgcn_mfma_f32_16x16x32_bf16(kf[m], qf[ks][n], sa[m][n], 0, 0, 0);
        }
        __builtin_amdgcn_s_setprio(0);
        __syncthreads();                       // Ksm free
        if (kt < 7) stage128(Kg + (size_t)((kt + 1) * 128) * 1024, Ksm, tid);
        #pragma unroll
        for (int n = 0; n < 8; ++n)
            #pragma unroll
            for (int m = 0; m < 2; ++m)
                #pragma unroll
                for (int r = 0; r < 4; ++r)
                    rs_p[n] += exp2f(fmaf(sa[m][n][r], C1E, C2E));
    }
    #pragma unroll
    for (int n = 0; n < 8; ++n) {
        rs_p[n] += __shfl_xor(rs_p[n], 16);
        rs_p[n] += __shfl_xor(rs_p[n], 32);
    }
    if (lane < 16) {
        #pragma unroll
        for (int n = 0; n < 8; ++n) rs4[w][n * 16 + lane] = rs_p[n];
    }
    __syncthreads();
    if (tid < 128) {
        float l = rs4[0][tid] + rs4[1][tid] + rs4[2][tid] + rs4[3][tid];
        lt[tid] = C2E - __log2f(l);            // exp2(s*C1 + lt) = exp(s/8-8)/l
    }
    stage128(Kg, Ksm, tid);                    // K(0) for loop 2

    // ---- loop 2: normalized attn write + PV ----
    f32x4 oa[2][4] = {};
    float* attnq = attn + ((size_t)bh * 1024 + qt * 128) * 1024;
    for (int kt = 0; kt < 8; ++kt) {
        __syncthreads();                       // K(kt) ready; Vsm free; lt visible
        stage64x256(Vg + kt * 128, Vsm, tid);  // V(kt), drained by barrier B
        f32x4 sa[2][8] = {};
        __builtin_amdgcn_s_setprio(1);
        #pragma unroll
        for (int ks = 0; ks < 2; ++ks) {
            const int kb = ks * 64 + (lane >> 4) * 16;
            bf16x8 kf[2];
            #pragma unroll
            for (int m = 0; m < 2; ++m) {
                int row = w * 32 + m * 16 + (lane & 15);
                kf[m] = *(const bf16x8*)(Ksm + ((row * 128 + kb) ^ ((row & 7) << 4)));
            }
            #pragma unroll
            for (int m = 0; m < 2; ++m)
                #pragma unroll
                for (int n = 0; n < 8; ++n)
                    sa[m][n] = __builtin_amdgcn_mfma_f32_16x16x32_bf16(kf[m], qf[ks][n], sa[m][n], 0, 0, 0);
        }
        __builtin_amdgcn_s_setprio(0);
        // normalized P: attn f32 store + bf16 pack into Psm
        #pragma unroll
        for (int n = 0; n < 8; ++n) {
            int q = n * 16 + (lane & 15);
            float ltq = lt[q];
            #pragma unroll
            for (int m = 0; m < 2; ++m) {
                int k0 = w * 32 + m * 16 + (lane >> 4) * 4;
                float4 p4;
                p4.x = exp2f(fmaf(sa[m][n][0], C1E, ltq));
                p4.y = exp2f(fmaf(sa[m][n][1], C1E, ltq));
                p4.z = exp2f(fmaf(sa[m][n][2], C1E, ltq));
                p4.w = exp2f(fmaf(sa[m][n][3], C1E, ltq));
                *(float4*)(attnq + (size_t)q * 1024 + kt * 128 + k0) = p4;
                uint2 pk;
                pk.x = f2b(p4.x) | ((unsigned)f2b(p4.y) << 16);
                pk.y = f2b(p4.z) | ((unsigned)f2b(p4.w) << 16);
                *(uint2*)(Psm + ((q * 256 + k0 * 2) ^ ((q & 7) << 4))) = pk;
            }
        }
        __syncthreads();                       // B: Psm ready; V(kt) drained; Ksm free
        if (kt < 7) stage128(Kg + (size_t)((kt + 1) * 128) * 1024, Ksm, tid);
        __builtin_amdgcn_s_setprio(1);
        #pragma unroll
        for (int ks = 0; ks < 4; ++ks) {
            const int kb = ks * 64 + (lane >> 4) * 16;
            bf16x8 pa[2], vb[4];
            #pragma unroll
            for (int m2 = 0; m2 < 2; ++m2) {
                int row = w * 32 + m2 * 16 + (lane & 15);
                pa[m2] = *(const bf16x8*)(Psm + ((row * 256 + kb) ^ ((row & 7) << 4)));
            }
            #pragma unroll
            for (int n2 = 0; n2 < 4; ++n2) {
                int d = n2 * 16 + (lane & 15);
                vb[n2] = *(const bf16x8*)(Vsm + d * 256 + (kb ^ ((d & 7) << 4)));
            }
            #pragma unroll
            for (int m2 = 0; m2 < 2; ++m2)
                #pragma unroll
                for (int n2 = 0; n2 < 4; ++n2)
                    oa[m2][n2] = __builtin_amdgcn_mfma_f32_16x16x32_bf16(pa[m2], vb[n2], oa[m2][n2], 0, 0, 0);
        }
        __builtin_amdgcn_s_setprio(0);
    }
    unsigned short* Ob = Og + (size_t)(b * 1024 + qt * 128) * 1024 + h * 64;
    #pragma unroll
    for (int m2 = 0; m2 < 2; ++m2)
        #pragma unroll
        for (int n2 = 0; n2 < 4; ++n2) {
            int d = n2 * 16 + (lane & 15);
            #pragma unroll
            for (int r = 0; r < 4; ++r) {
                int qrow = w * 32 + m2 * 16 + (lane >> 4) * 4 + r;
                Ob[(size_t)qrow * 1024 + d] = f2b(oa[m2][n2][r]);
            }
        }
}

extern "C" void kernel_launch(void* const* d_in, const int* in_sizes, int n_in,
                              void* d_out, int out_size, void* d_ws, size_t ws_size,
                              hipStream_t stream) {
    (void)in_sizes; (void)n_in; (void)out_size; (void)ws_size;
    const float* q    = (const float*)d_in[0];
    const float* Wq_w = (const float*)d_in[1];
    const float* Wq_b = (const float*)d_in[2];
    const float* Wk_w = (const float*)d_in[3];
    const float* Wk_b = (const float*)d_in[4];
    const float* Wv_w = (const float*)d_in[5];
    const float* Wv_b = (const float*)d_in[6];
    const float* Wo_w = (const float*)d_in[7];
    const float* Wo_b = (const float*)d_in[8];

    char* ws = (char*)d_ws;                              // ws use: 48 MiB
    unsigned short* Qws  = (unsigned short*)(ws);        // Q bf16, later O bf16
    unsigned short* Kws  = (unsigned short*)(ws + (16u << 20));  // K bf16, later Wo bf16
    unsigned short* VTws = (unsigned short*)(ws + (32u << 20));

    float* outp  = (float*)d_out;                        // f32 out [8,1024,1024]
    float* attnp = outp + 8388608;                       // f32 attn [8,16,1024,1024]

    // bf16 scratch inside attn region (free until fused_attn writes it)
    char* scr = (char*)attnp;
    unsigned short* qbf = (unsigned short*)scr;                    // 16 MiB
    unsigned short* wqb = (unsigned short*)(scr + (16u << 20));
    unsigned short* wkb = (unsigned short*)(scr + (18u << 20));
    unsigned short* wvb = (unsigned short*)(scr + (20u << 20));

    dim3 blk(256);
    conv_all<<<dim3(4096 + 3 * 512), blk, 0, stream>>>(q, Wq_w, Wk_w, Wv_w, qbf, wqb, wkb, wvb);
    qkv_proj<<<dim3(1024), blk, 0, stream>>>(qbf, wqb, wkb, wvb, Wq_b, Wk_b, Wv_b, Qws, Kws, VTws);
    fused_attn<<<dim3(1024), blk, 0, stream>>>(Qws, Kws, VTws, attnp, Qws);
    conv_bf16<<<dim3(512), blk, 0, stream>>>(Wo_w, Kws);           // Kws free now
    proj_o<<<dim3(512), blk, 0, stream>>>(Qws, Kws, Wo_b, outp);
}